// Round 13
// baseline (663.678 us; speedup 1.0000x reference)
//
#include <hip/hip_runtime.h>
#include <hip/hip_bf16.h>

// GraphCastEdgeBlock fused kernel for MI355X (gfx950).
// h = silu(LN(concat(ea, ns[src], nd[dst]) @ W1 + b1)); out = ea + h @ W2 + b2
// E=600000, N=50000, D=128, H=512, in=384. fp32 I/O; bf16 MFMA compute.
// r12 skeleton (MTILE=64, 8 waves, 16x16x32, ring-6 post-LN, spill-free) +
// pair-packed (cvt_pk) staging and LN writes; LN pairing enabled by a
// k-permutation baked into W2t (validated in r10). Plain epilogue stores.

#define E_TOTAL 600000
#define DD      128
#define HH      512
#define IND     384
#define MTILE   64
#define XS      520   // LDS row stride (bf16 elems); 1040 B (260 words = 4 mod 32)

typedef __attribute__((ext_vector_type(8))) short bf16x8;
typedef __attribute__((ext_vector_type(4))) float f32x4;

__device__ __forceinline__ ushort f2bf(float f) {
    __hip_bfloat16 b = __float2bfloat16(f);
    return *reinterpret_cast<ushort*>(&b);
}
// pack two f32 -> one u32 of 2 bf16; native -> v_cvt_pk_bf16_f32
__device__ __forceinline__ uint pk2(float a, float b) {
    __hip_bfloat162 h = __float22bfloat162_rn(float2{a, b});
    return *reinterpret_cast<uint*>(&h);
}

template <int CTRL>
__device__ __forceinline__ float dpp_add(float x) {
    union { float f; int i; } a, b;
    a.f = x;
    b.i = __builtin_amdgcn_update_dpp(0, a.i, CTRL, 0xf, 0xf, true);
    return x + b.f;
}
// sum across each 16-lane row (all lanes get the sum); pure VALU, no DS
__device__ __forceinline__ float row16_sum(float s) {
    s = dpp_add<0xB1>(s);    // quad_perm xor1
    s = dpp_add<0x4E>(s);    // quad_perm xor2
    s = dpp_add<0x124>(s);   // row_ror:4
    s = dpp_add<0x128>(s);   // row_ror:8
    return s;
}

// W1 [384][512] f32 -> W1t [512][384] bf16 (plain transpose).
// W2 [512][128] f32 -> W2t [128][512] bf16 with k-PERMUTED columns matching
// the LN pair-packed act layout (r10-validated):
//   jj = b64*64 + q*32 + li*2 + lo  <->  k = b64*64 + (q*2+lo)*16 + li
__global__ void prep_weights(const float* __restrict__ W1, const float* __restrict__ W2,
                             ushort* __restrict__ W1t, ushort* __restrict__ W2t) {
    int j = blockIdx.x * 256 + threadIdx.x;
    if (j < IND * HH) {
        int n = j / IND, k = j % IND;
        W1t[j] = f2bf(W1[k * HH + n]);
    }
    int j2 = j - IND * HH;
    if (j2 >= 0 && j2 < HH * DD) {
        int d2 = j2 / HH, jj = j2 % HH;
        int b64 = jj >> 6, r6 = jj & 63;
        int q = r6 >> 5, r5 = r6 & 31;
        int li = r5 >> 1, lo = r5 & 1;
        int k = b64 * 64 + (q * 2 + lo) * 16 + li;
        W2t[j2] = f2bf(W2[k * DD + d2]);
    }
}

__global__ __launch_bounds__(512, 4) void edge_block_kernel(
    const float* __restrict__ edge_attr,
    const float* __restrict__ nsrc,
    const float* __restrict__ ndst,
    const int*   __restrict__ eidx,
    const float* __restrict__ b1,
    const float* __restrict__ g1,
    const float* __restrict__ be1,
    const float* __restrict__ b2,
    const ushort* __restrict__ W1t,
    const ushort* __restrict__ W2t,
    float* __restrict__ out)
{
    __shared__ __align__(16) ushort xbuf[MTILE * XS];  // 66560 B (x, then act)
    __shared__ float red_s[MTILE][8];
    __shared__ float red_q[MTILE][8];
    __shared__ __align__(8) float stats[MTILE][2];

    const int tid  = threadIdx.x;
    const int e0   = blockIdx.x * MTILE;
    const int lane = tid & 63;
    const int w    = tid >> 6;          // wave 0..7
    const int g    = lane >> 4;         // quarter-wave 0..3
    const int li   = lane & 15;

    // ---- 1) stage x tile [64][384] -> LDS bf16 (pk2 packed); eidx hoisted ----
    {
        const int l32 = tid & 31, grp = tid >> 5;    // 16 groups of 32 lanes
        int si[4], di[4];
        #pragma unroll
        for (int it = 0; it < 4; ++it) {
            const int e = e0 + grp + it * 16;
            si[it] = eidx[e];
            di[it] = eidx[E_TOTAL + e];
        }
        #pragma unroll
        for (int it = 0; it < 4; ++it) {
            const int r = grp + it * 16;
            const int e = e0 + r;
            float4 ea = *(const float4*)&edge_attr[(size_t)e * DD + l32 * 4];
            float4 sf = *(const float4*)&nsrc[(size_t)si[it] * DD + l32 * 4];
            float4 df = *(const float4*)&ndst[(size_t)di[it] * DD + l32 * 4];
            ushort* row = &xbuf[r * XS];
            uint2 ua = { pk2(ea.x, ea.y), pk2(ea.z, ea.w) };
            uint2 us = { pk2(sf.x, sf.y), pk2(sf.z, sf.w) };
            uint2 ud = { pk2(df.x, df.y), pk2(df.z, df.w) };
            *(uint2*)&row[  0 + l32 * 4] = ua;
            *(uint2*)&row[128 + l32 * 4] = us;
            *(uint2*)&row[256 + l32 * 4] = ud;
        }
    }
    __syncthreads();   // A

    // ---- 2) GEMM1: h[64][512] = x @ W1; wave w owns cols [w*64, w*64+64) ----
    const int wn0 = w * 64;
    f32x4 acc[4][4];
    #pragma unroll
    for (int mi = 0; mi < 4; ++mi)
        #pragma unroll
        for (int ni = 0; ni < 4; ++ni)
            acc[mi][ni] = (f32x4){0.f, 0.f, 0.f, 0.f};

    const ushort* w1p = W1t + (size_t)(wn0 + li) * IND + g * 8;

    bf16x8 B1b[2][4];
    #pragma unroll
    for (int ni = 0; ni < 4; ++ni) B1b[0][ni] = *(const bf16x8*)(w1p + ni * 16 * IND);
    #pragma unroll
    for (int ni = 0; ni < 4; ++ni) B1b[1][ni] = *(const bf16x8*)(w1p + ni * 16 * IND + 32);

    #pragma unroll
    for (int kb = 0; kb < 12; ++kb) {
        const int cur = kb & 1;                  // compile-time after unroll
        const int ko  = kb * 32 + g * 8;
        bf16x8 a[4];
        #pragma unroll
        for (int mi = 0; mi < 4; ++mi)
            a[mi] = *(const bf16x8*)&xbuf[(mi * 16 + li) * XS + ko];
        __builtin_amdgcn_s_setprio(1);
        #pragma unroll
        for (int mi = 0; mi < 4; ++mi)
            #pragma unroll
            for (int ni = 0; ni < 4; ++ni)
                acc[mi][ni] = __builtin_amdgcn_mfma_f32_16x16x32_bf16(
                    a[mi], B1b[cur][ni], acc[mi][ni], 0, 0, 0);
        __builtin_amdgcn_s_setprio(0);
        if (kb < 10) {                           // prefetch depth 2
            #pragma unroll
            for (int ni = 0; ni < 4; ++ni)
                B1b[cur][ni] = *(const bf16x8*)(w1p + ni * 16 * IND + (kb + 2) * 32);
        }
    }

    // ---- 3) bias + row stats via DPP row-reduce ----
    float b1v[4], g1v[4], bev[4];
    #pragma unroll
    for (int ni = 0; ni < 4; ++ni) {
        int c = wn0 + ni * 16 + li;
        b1v[ni] = b1[c]; g1v[ni] = g1[c]; bev[ni] = be1[c];
    }

    #pragma unroll
    for (int mi = 0; mi < 4; ++mi) {
        #pragma unroll
        for (int reg = 0; reg < 4; ++reg) {
            float s = 0.f, q = 0.f;
            #pragma unroll
            for (int ni = 0; ni < 4; ++ni) {
                float h = acc[mi][ni][reg] + b1v[ni];
                acc[mi][ni][reg] = h;
                s += h;
                q = fmaf(h, h, q);
            }
            s = row16_sum(s);
            q = row16_sum(q);
            if (li == 0) {
                int row = mi * 16 + g * 4 + reg;
                red_s[row][w] = s;
                red_q[row][w] = q;
            }
        }
    }
    __syncthreads();   // B

    if (tid < MTILE) {
        float s = 0.f, q = 0.f;
        #pragma unroll
        for (int i = 0; i < 8; ++i) { s += red_s[tid][i]; q += red_q[tid][i]; }
        float mu  = s * (1.f / 512.f);
        float var = q * (1.f / 512.f) - mu * mu;
        stats[tid][0] = mu;
        stats[tid][1] = rsqrtf(var + 1e-5f);
    }
    __syncthreads();   // C

    // ---- 4) LN + SiLU -> act, pair-packed b32 writes (permuted k layout) ----
    uint* actu = (uint*)xbuf;                     // row stride 260 u32
    #pragma unroll
    for (int mi = 0; mi < 4; ++mi) {
        #pragma unroll
        for (int reg = 0; reg < 4; ++reg) {
            int row = mi * 16 + g * 4 + reg;
            float2 st = *(float2*)&stats[row][0];     // {mu, rstd}
            uint* arow = actu + row * (XS / 2);
            #pragma unroll
            for (int p = 0; p < 2; ++p) {
                // lo = 0: ni = 2p; lo = 1: ni = 2p+1  (cols 16 apart, packed)
                float sc0 = st.y * g1v[2 * p];
                float tc0 = fmaf(-st.x, sc0, bev[2 * p]);
                float xn0 = fmaf(acc[mi][2 * p][reg], sc0, tc0);
                float av0 = xn0 * __builtin_amdgcn_rcpf(1.f + __expf(-xn0));
                float sc1 = st.y * g1v[2 * p + 1];
                float tc1 = fmaf(-st.x, sc1, bev[2 * p + 1]);
                float xn1 = fmaf(acc[mi][2 * p + 1][reg], sc1, tc1);
                float av1 = xn1 * __builtin_amdgcn_rcpf(1.f + __expf(-xn1));
                arow[(wn0 >> 1) + p * 16 + li] = pk2(av0, av1);
            }
        }
    }

    // ---- 5) B2 ring-6 preload (24 VGPR; acc dead after LN) ----
    const ushort* w2p = W2t + (size_t)(w * 16 + li) * HH + g * 8;
    bf16x8 B2r[6];
    #pragma unroll
    for (int i = 0; i < 6; ++i) B2r[i] = *(const bf16x8*)(w2p + i * 32);

    // residual loads (latency hides under barrier + GEMM2)
    float earr[4][4];
    #pragma unroll
    for (int mi = 0; mi < 4; ++mi)
        #pragma unroll
        for (int reg = 0; reg < 4; ++reg) {
            int row = mi * 16 + g * 4 + reg;
            earr[mi][reg] = edge_attr[(size_t)(e0 + row) * DD + w * 16 + li];
        }
    __syncthreads();   // D

    // ---- 6) GEMM2: out[64][128] = act @ W2 (permuted k); ring-6 streamed B ----
    f32x4 acc2[4];
    #pragma unroll
    for (int mi = 0; mi < 4; ++mi) acc2[mi] = (f32x4){0.f, 0.f, 0.f, 0.f};

    #pragma unroll
    for (int kb = 0; kb < 16; ++kb) {
        const int cur = kb % 6;                  // compile-time after unroll
        bf16x8 bf = B2r[cur];
        if (kb < 10)
            B2r[cur] = *(const bf16x8*)(w2p + (kb + 6) * 32);
        const int ko = kb * 32 + g * 8;
        bf16x8 a2[4];
        #pragma unroll
        for (int mi = 0; mi < 4; ++mi)
            a2[mi] = *(const bf16x8*)&xbuf[(mi * 16 + li) * XS + ko];
        __builtin_amdgcn_s_setprio(1);
        #pragma unroll
        for (int mi = 0; mi < 4; ++mi)
            acc2[mi] = __builtin_amdgcn_mfma_f32_16x16x32_bf16(a2[mi], bf, acc2[mi], 0, 0, 0);
        __builtin_amdgcn_s_setprio(0);
    }

    // ---- 7) epilogue: plain direct stores, out = acc2 + b2 + ea(regs) ----
    const float b2v = b2[w * 16 + li];
    #pragma unroll
    for (int mi = 0; mi < 4; ++mi) {
        #pragma unroll
        for (int reg = 0; reg < 4; ++reg) {
            int row = mi * 16 + g * 4 + reg;
            size_t o = (size_t)(e0 + row) * DD + w * 16 + li;
            out[o] = acc2[mi][reg] + b2v + earr[mi][reg];
        }
    }
}

extern "C" void kernel_launch(void* const* d_in, const int* in_sizes, int n_in,
                              void* d_out, int out_size, void* d_ws, size_t ws_size,
                              hipStream_t stream) {
    const float* edge_attr = (const float*)d_in[0];
    const float* nsrc      = (const float*)d_in[1];
    const float* ndst      = (const float*)d_in[2];
    const int*   eidx      = (const int*)d_in[3];
    const float* W1        = (const float*)d_in[4];
    const float* b1        = (const float*)d_in[5];
    const float* g1        = (const float*)d_in[6];
    const float* be1       = (const float*)d_in[7];
    const float* W2        = (const float*)d_in[8];
    const float* b2        = (const float*)d_in[9];
    float* out = (float*)d_out;

    ushort* W1t = (ushort*)d_ws;             // 512*384 bf16 = 384 KiB
    ushort* W2t = W1t + IND * HH;            // 128*512 bf16 = 128 KiB

    hipLaunchKernelGGL(prep_weights,
                       dim3((IND * HH + HH * DD + 255) / 256), dim3(256), 0, stream,
                       W1, W2, W1t, W2t);

    hipLaunchKernelGGL(edge_block_kernel,
                       dim3(E_TOTAL / MTILE), dim3(512), 0, stream,
                       edge_attr, nsrc, ndst, eidx, b1, g1, be1, b2, W1t, W2t, out);
}